// Round 5
// baseline (1160.483 us; speedup 1.0000x reference)
//
#include <hip/hip_runtime.h>
#include <math.h>

// ---------------------------------------------------------------------------
// GATv2 block: LN+ReLU -> x_l(fp16)/x_r(fp32) GEMMs (split-bf16 MFMA) ->
// bucketed CSR build -> fused score+softmax+aggregate -> head mean + bias.
// ---------------------------------------------------------------------------

typedef __bf16 bf16x8 __attribute__((ext_vector_type(8)));
typedef float f32x4 __attribute__((ext_vector_type(4)));
typedef _Float16 half2v __attribute__((ext_vector_type(2)));

static __device__ __forceinline__ unsigned short f2bf(float f) {
  union { float f; unsigned u; } v;
  v.f = f;
  const unsigned r = v.u + 0x7fffu + ((v.u >> 16) & 1u);  // RNE
  return (unsigned short)(r >> 16);
}
static __device__ __forceinline__ float bf2f(unsigned short h) {
  union { float f; unsigned u; } v;
  v.u = ((unsigned)h) << 16;
  return v.f;
}

// ---------------- K0: split W into bf16 hi/lo, B-fragment layout -----------
__global__ __launch_bounds__(256) void pack_w_k(
    const float* __restrict__ Wl, const float* __restrict__ Wr,
    unsigned short* __restrict__ wph, unsigned short* __restrict__ wpl) {
  const int idx = blockIdx.x * 256 + threadIdx.x;  // 0..32767
  const int mat = idx >> 14;
  const int rem = idx & 16383;   // k*128 + c
  const int k = rem >> 7;
  const int c = rem & 127;
  const float v = (mat ? Wr : Wl)[rem];
  const unsigned short h = f2bf(v);
  const unsigned short lo = f2bf(v - bf2f(h));
  const int po = ((mat * 4 + (k >> 5)) * 128 + c) * 32 + (k & 31);
  wph[po] = h;
  wpl[po] = lo;
}

// ---------------- K1: LN+ReLU + dual GEMM, 128-row tiles -------------------
// 4 waves: w0/w1 -> xl (fp16) cols 0-63/64-127 ; w2/w3 -> xr (fp32).
// D = Ah*Bh + Al*Bh + Ah*Bl (fp32-emulated bf16 MFMA).
__global__ __launch_bounds__(256, 2) void ln_gemm_mfma_k(
    const float* __restrict__ x, const float* __restrict__ gamma,
    const float* __restrict__ beta,
    const unsigned short* __restrict__ wph,
    const unsigned short* __restrict__ wpl,
    const float* __restrict__ bl, const float* __restrict__ br,
    _Float16* __restrict__ xl16, float* __restrict__ xr, int n) {
  __shared__ unsigned short ah[128 * 136];
  __shared__ unsigned short al[128 * 136];

  const int t = threadIdx.x;
  const int blk = blockIdx.x * 128;

  // ---- LN + ReLU + hi/lo split: 2 halves of 64 rows, 4 lanes per row ----
#pragma unroll
  for (int half = 0; half < 2; half++) {
    const int r = t >> 2, q = t & 3;
    const int row = half * 64 + r;
    const int node = blk + row;
    float4 v[8];
    float s = 0.f, s2 = 0.f;
    const float* xrow = x + (size_t)node * 128;
#pragma unroll
    for (int rep = 0; rep < 8; rep++) {
      float4 f = make_float4(0.f, 0.f, 0.f, 0.f);
      if (node < n) f = *(const float4*)(xrow + 4 * q + 16 * rep);
      v[rep] = f;
      s += f.x + f.y + f.z + f.w;
      s2 += f.x * f.x + f.y * f.y + f.z * f.z + f.w * f.w;
    }
    s += __shfl_xor(s, 1);  s += __shfl_xor(s, 2);
    s2 += __shfl_xor(s2, 1); s2 += __shfl_xor(s2, 2);
    const float mu = s * (1.f / 128.f);
    const float rs = rsqrtf(s2 * (1.f / 128.f) - mu * mu + 1e-5f);
#pragma unroll
    for (int rep = 0; rep < 8; rep++) {
      const int k0 = 4 * q + 16 * rep;
      const float4 g4 = *(const float4*)(gamma + k0);
      const float4 b4 = *(const float4*)(beta + k0);
      const float ev[4] = {v[rep].x, v[rep].y, v[rep].z, v[rep].w};
      const float gv[4] = {g4.x, g4.y, g4.z, g4.w};
      const float bv[4] = {b4.x, b4.y, b4.z, b4.w};
      unsigned short hs[4], ls[4];
#pragma unroll
      for (int i2 = 0; i2 < 4; i2++) {
        float xv = (ev[i2] - mu) * rs * gv[i2] + bv[i2];
        xv = fmaxf(xv, 0.f);
        const unsigned short h = f2bf(xv);
        hs[i2] = h;
        ls[i2] = f2bf(xv - bf2f(h));
      }
      *(ushort4*)(&ah[row * 136 + k0]) = make_ushort4(hs[0], hs[1], hs[2], hs[3]);
      *(ushort4*)(&al[row * 136 + k0]) = make_ushort4(ls[0], ls[1], ls[2], ls[3]);
    }
  }
  __syncthreads();

  // ---- MFMA phase: each wave = 128 rows x 64 cols ----
  const int lane = t & 63;
  const int w = t >> 6;
  const int mat = w >> 1;           // 0 -> xl16, 1 -> xr
  const int cbase = (w & 1) * 64;
  const int m16 = lane & 15;
  const int quad = lane >> 4;
  const float* const biasp = mat ? br : bl;

#pragma unroll
  for (int ct = 0; ct < 4; ct++) {
    const int c = cbase + ct * 16 + m16;
    bf16x8 Bh[4], Bl8[4];
#pragma unroll
    for (int kb = 0; kb < 4; kb++) {
      const int bo = ((mat * 4 + kb) * 128 + c) * 32 + quad * 8;
      Bh[kb]  = *(const bf16x8*)(wph + bo);
      Bl8[kb] = *(const bf16x8*)(wpl + bo);
    }
    const float bc = biasp[c];
#pragma unroll
    for (int rt = 0; rt < 8; rt++) {
      f32x4 a = {0.f, 0.f, 0.f, 0.f};
#pragma unroll
      for (int kb = 0; kb < 4; kb++) {
        const int ao = (rt * 16 + m16) * 136 + kb * 32 + quad * 8;
        const bf16x8 Ah  = *(const bf16x8*)(ah + ao);
        const bf16x8 Al8 = *(const bf16x8*)(al + ao);
        a = __builtin_amdgcn_mfma_f32_16x16x32_bf16(Ah,  Bh[kb],  a, 0, 0, 0);
        a = __builtin_amdgcn_mfma_f32_16x16x32_bf16(Al8, Bh[kb],  a, 0, 0, 0);
        a = __builtin_amdgcn_mfma_f32_16x16x32_bf16(Ah,  Bl8[kb], a, 0, 0, 0);
      }
      // C/D: col = lane&15, row = quad*4 + reg  [m89-verified]
#pragma unroll
      for (int g = 0; g < 4; g++) {
        const int row = blk + rt * 16 + quad * 4 + g;
        if (row < n) {
          const float o = a[g] + bc;
          if (mat == 0) {
            xl16[(size_t)row * 128 + c] = (_Float16)o;
          } else {
            __builtin_nontemporal_store(o, &xr[(size_t)row * 128 + c]);
          }
        }
      }
    }
  }
}

// ---------------- K2a: bucket histogram (bucket = dst >> 7) ----------------
__global__ __launch_bounds__(256) void bucket_hist_k(
    const int* __restrict__ dst_arr, int* __restrict__ bucket_cnt, int E) {
  const int base = (blockIdx.x * 256 + threadIdx.x) * 4;
  if (base >= E) return;
  if (base + 4 <= E) {
    const int4 d4 = *(const int4*)(dst_arr + base);
    atomicAdd(&bucket_cnt[d4.x >> 7], 1);
    atomicAdd(&bucket_cnt[d4.y >> 7], 1);
    atomicAdd(&bucket_cnt[d4.z >> 7], 1);
    atomicAdd(&bucket_cnt[d4.w >> 7], 1);
  } else {
    for (int k = base; k < E; k++) atomicAdd(&bucket_cnt[dst_arr[k] >> 7], 1);
  }
}

// ---------------- K2b: scan bucket counts (NB <= 1024, one block) ----------
__global__ __launch_bounds__(1024) void bucket_scan_k(
    const int* __restrict__ bucket_cnt, int* __restrict__ bucket_edge_off,
    int* __restrict__ bucket_cur, int* __restrict__ offsets,
    int NB, int N, int M) {
  __shared__ int lds[1024];
  const int t = threadIdx.x;
  const int v = (t < NB) ? bucket_cnt[t] : 0;
  lds[t] = v;
  __syncthreads();
  for (int d = 1; d < 1024; d <<= 1) {
    int u = 0;
    if (t >= d) u = lds[t - d];
    __syncthreads();
    lds[t] += u;
    __syncthreads();
  }
  if (t < NB) {
    const int excl = lds[t] - v;
    bucket_edge_off[t] = excl;
    bucket_cur[t] = excl;
    if (t == NB - 1) bucket_edge_off[NB] = lds[t];  // = E
  }
  if (t == 0) offsets[N] = M;
}

// ---------------- K2c: bin edges into bucket-contiguous regions ------------
__global__ __launch_bounds__(256) void bin_k(const int* __restrict__ ei,
                                             int* __restrict__ bucket_cur,
                                             int2* __restrict__ binned, int E) {
  const int base = (blockIdx.x * 256 + threadIdx.x) * 4;
  if (base >= E) return;
  if (base + 4 <= E) {
    const int4 s4 = *(const int4*)(ei + base);
    const int4 d4 = *(const int4*)(ei + E + base);
    binned[atomicAdd(&bucket_cur[d4.x >> 7], 1)] = make_int2(s4.x, d4.x);
    binned[atomicAdd(&bucket_cur[d4.y >> 7], 1)] = make_int2(s4.y, d4.y);
    binned[atomicAdd(&bucket_cur[d4.z >> 7], 1)] = make_int2(s4.z, d4.z);
    binned[atomicAdd(&bucket_cur[d4.w >> 7], 1)] = make_int2(s4.w, d4.w);
  } else {
    for (int k = base; k < E; k++) {
      const int s = ei[k], d = ei[E + k];
      binned[atomicAdd(&bucket_cur[d >> 7], 1)] = make_int2(s, d);
    }
  }
}

// ---------------- K2d: per-bucket CSR segment (LDS hist/scan/cursors) ------
// One block per bucket of 128 nodes. csr base = edge_scan[b] + 128*b (each
// prior node contributes exactly 1 self-loop). Self-loop placed first.
__global__ __launch_bounds__(256) void csr_build_k(
    const int2* __restrict__ binned, const int* __restrict__ bucket_edge_off,
    int* __restrict__ csr_src, int* __restrict__ offsets, int N) {
  __shared__ int s_cnt[128];
  __shared__ int s_off[128];
  __shared__ int s_cur[128];
  const int b = blockIdx.x;
  const int t = threadIdx.x;
  const int eb = bucket_edge_off[b];
  const int ee = bucket_edge_off[b + 1];
  const int node0 = b << 7;
  if (t < 128) s_cnt[t] = 0;
  __syncthreads();
  for (int j = eb + t; j < ee; j += 256) {
    const int2 e = binned[j];
    atomicAdd(&s_cnt[e.y & 127], 1);
  }
  __syncthreads();
  int w = 0;
  if (t < 128) w = (node0 + t < N) ? (s_cnt[t] + 1) : 0;  // +1 self-loop
  if (t < 128) s_off[t] = w;
  __syncthreads();
  for (int d = 1; d < 128; d <<= 1) {
    int u = 0;
    if (t < 128 && t >= d) u = s_off[t - d];
    __syncthreads();
    if (t < 128) s_off[t] += u;
    __syncthreads();
  }
  const int base = eb + node0;
  if (t < 128) {
    const int excl = s_off[t] - w;   // exclusive local offset
    const int node = node0 + t;
    if (node < N) {
      offsets[node] = base + excl;
      csr_src[base + excl] = node;   // self-loop first
      s_cur[t] = excl + 1;
    }
  }
  __syncthreads();
  for (int j = eb + t; j < ee; j += 256) {
    const int2 e = binned[j];
    const int pos = atomicAdd(&s_cur[e.y & 127], 1);
    csr_src[base + pos] = e.x;
  }
}

// ---------------- K5: fused score + softmax + aggregate (wave/node) --------
// xl gathered as fp16 (halves gather bytes); xr/scores/accum in fp32.
__global__ __launch_bounds__(256) void agg_fused_k(
    const half2v* __restrict__ xl16, const float* __restrict__ xr,
    const float* __restrict__ att, const int* __restrict__ csr_src,
    const int* __restrict__ offsets, const float* __restrict__ bias,
    float* __restrict__ out, int n) {
  __shared__ float att_s[128];
  const int t = threadIdx.x;
  if (t < 128) att_s[t] = att[t];
  __syncthreads();

  const int wid = t >> 6;
  const int lane = t & 63;
  const int i = blockIdx.x * 4 + wid;
  if (i >= n) return;
  const int c = lane * 2;
  const int off = offsets[i];
  const int end = offsets[i + 1];

  const float2 b2 = *(const float2*)(bias + (c & 31));
  const float2 xr2 = *(const float2*)(xr + (size_t)i * 128 + c);
  const float2 at2 = *(const float2*)(att_s + c);

  float den = 0.f, accx = 0.f, accy = 0.f;

  half2v xvA[4];
#pragma unroll
  for (int k = 0; k < 4; k++) {
    const int jj = off + k < end ? off + k : end - 1;
    const int s = csr_src[jj];
    xvA[k] = xl16[(size_t)s * 64 + lane];
  }

  for (int j = off; j < end; j += 4) {
    float2 xv[4];
#pragma unroll
    for (int k = 0; k < 4; k++)
      xv[k] = make_float2((float)xvA[k].x, (float)xvA[k].y);
    const int jn = j + 4;
    if (jn < end) {
#pragma unroll
      for (int k = 0; k < 4; k++) {
        const int jj = jn + k < end ? jn + k : end - 1;
        const int s = csr_src[jj];
        xvA[k] = xl16[(size_t)s * 64 + lane];
      }
    }

    float p[4];
#pragma unroll
    for (int k = 0; k < 4; k++) {
      const float vx = xv[k].x + xr2.x;
      const float vy = xv[k].y + xr2.y;
      const float lx = fmaxf(vx, 0.2f * vx);
      const float ly = fmaxf(vy, 0.2f * vy);
      p[k] = fmaf(lx, at2.x, ly * at2.y);
    }
#pragma unroll
    for (int d = 1; d <= 8; d <<= 1) {
#pragma unroll
      for (int k = 0; k < 4; k++) p[k] += __shfl_xor(p[k], d);
    }
#pragma unroll
    for (int k = 0; k < 4; k++) {
      const float wgt = (j + k < end) ? __expf(p[k]) : 0.f;
      den += wgt;
      accx = fmaf(wgt, xv[k].x, accx);
      accy = fmaf(wgt, xv[k].y, accy);
    }
  }

  const float rd = 1.0f / (den + 1e-16f);
  accx *= rd;
  accy *= rd;
  accx += __shfl_xor(accx, 16); accy += __shfl_xor(accy, 16);
  accx += __shfl_xor(accx, 32); accy += __shfl_xor(accy, 32);
  if (lane < 16) {
    *(float2*)(out + (size_t)i * 32 + c) =
        make_float2(accx * 0.25f + b2.x, accy * 0.25f + b2.y);
  }
}

// ---------------------------------------------------------------------------
extern "C" void kernel_launch(void* const* d_in, const int* in_sizes, int n_in,
                              void* d_out, int out_size, void* d_ws,
                              size_t ws_size, hipStream_t stream) {
  const float* x     = (const float*)d_in[0];
  const int*   ei    = (const int*)d_in[1];
  const float* gamma = (const float*)d_in[2];
  const float* beta  = (const float*)d_in[3];
  const float* Wl    = (const float*)d_in[4];
  const float* bl    = (const float*)d_in[5];
  const float* Wr    = (const float*)d_in[6];
  const float* br    = (const float*)d_in[7];
  const float* att   = (const float*)d_in[8];
  const float* bias  = (const float*)d_in[9];
  float* out = (float*)d_out;

  const int N = in_sizes[0] / 128;
  const int E = in_sizes[1] / 2;
  const int M = E + N;
  const int NB = (N + 127) / 128;   // 782 buckets of 128 nodes

  char* p = (char*)d_ws;
  size_t o = 0;
  auto alloc = [&](size_t bytes) -> void* {
    void* r = (void*)(p + o);
    o = (o + bytes + 255) & ~(size_t)255;
    return r;
  };
  // xl16 region doubles as the binned-edge buffer during CSR build
  // (binned: E*8 B = 12.8 MB <= xl16: N*128*2 B = 25.6 MB; CSR build
  // completes before the GEMM writes xl16).
  _Float16* xl16   = (_Float16*)alloc((size_t)N * 128 * 2);
  int2*     binned = (int2*)xl16;
  float* xr      = (float*)alloc((size_t)N * 128 * 4);
  int*   csr_src = (int*)alloc((size_t)M * 4);
  int*   offsets = (int*)alloc((size_t)(N + 1) * 4);
  int*   bucket_cnt = (int*)alloc((size_t)NB * 4);
  int*   bucket_off = (int*)alloc((size_t)(NB + 1) * 4);
  int*   bucket_cur = (int*)alloc((size_t)NB * 4);
  unsigned short* wph = (unsigned short*)alloc(2 * 128 * 128 * 2);
  unsigned short* wpl = (unsigned short*)alloc(2 * 128 * 128 * 2);
  (void)n_in; (void)out_size; (void)ws_size;

  // ---- CSR build (uses binned == xl16 region; runs before GEMM) ----
  hipMemsetAsync(bucket_cnt, 0, (size_t)NB * 4, stream);
  bucket_hist_k<<<(E / 4 + 255) / 256, 256, 0, stream>>>(ei + E, bucket_cnt, E);
  bucket_scan_k<<<1, 1024, 0, stream>>>(bucket_cnt, bucket_off, bucket_cur,
                                        offsets, NB, N, M);
  bin_k<<<(E / 4 + 255) / 256, 256, 0, stream>>>(ei, bucket_cur, binned, E);
  csr_build_k<<<NB, 256, 0, stream>>>(binned, bucket_off, csr_src, offsets, N);

  // ---- GEMM (overwrites xl16 region) ----
  pack_w_k<<<128, 256, 0, stream>>>(Wl, Wr, wph, wpl);
  ln_gemm_mfma_k<<<(N + 127) / 128, 256, 0, stream>>>(x, gamma, beta, wph, wpl,
                                                      bl, br, xl16, xr, N);

  // ---- fused attention aggregate ----
  agg_fused_k<<<(N + 3) / 4, 256, 0, stream>>>((const half2v*)xl16, xr, att,
                                               csr_src, offsets, bias, out, N);
}

// Round 7
// 451.885 us; speedup vs baseline: 2.5681x; 2.5681x over previous
//
#include <hip/hip_runtime.h>
#include <math.h>

// ---------------------------------------------------------------------------
// GATv2 block: LN+ReLU -> x_l(fp16)/x_r(fp32) GEMMs (split-bf16 MFMA) ->
// LDS-aggregated bucketed CSR build -> fused score+softmax+aggregate ->
// head mean + bias.
// ---------------------------------------------------------------------------

typedef __bf16 bf16x8 __attribute__((ext_vector_type(8)));
typedef float f32x4 __attribute__((ext_vector_type(4)));
typedef _Float16 half2v __attribute__((ext_vector_type(2)));

#define BIN_T 16384          // edges per block in hist/bin kernels
#define NB_MAX 1024          // max buckets (N <= 131072)

static __device__ __forceinline__ unsigned short f2bf(float f) {
  union { float f; unsigned u; } v;
  v.f = f;
  const unsigned r = v.u + 0x7fffu + ((v.u >> 16) & 1u);  // RNE
  return (unsigned short)(r >> 16);
}
static __device__ __forceinline__ float bf2f(unsigned short h) {
  union { float f; unsigned u; } v;
  v.u = ((unsigned)h) << 16;
  return v.f;
}

// ---------------- K0: split W into bf16 hi/lo, B-fragment layout -----------
__global__ __launch_bounds__(256) void pack_w_k(
    const float* __restrict__ Wl, const float* __restrict__ Wr,
    unsigned short* __restrict__ wph, unsigned short* __restrict__ wpl) {
  const int idx = blockIdx.x * 256 + threadIdx.x;  // 0..32767
  const int mat = idx >> 14;
  const int rem = idx & 16383;   // k*128 + c
  const int k = rem >> 7;
  const int c = rem & 127;
  const float v = (mat ? Wr : Wl)[rem];
  const unsigned short h = f2bf(v);
  const unsigned short lo = f2bf(v - bf2f(h));
  const int po = ((mat * 4 + (k >> 5)) * 128 + c) * 32 + (k & 31);
  wph[po] = h;
  wpl[po] = lo;
}

// ---------------- K1: LN+ReLU + dual GEMM, 128-row tiles -------------------
// 4 waves: w0/w1 -> xl (fp16) cols 0-63/64-127 ; w2/w3 -> xr (fp32).
// D = Ah*Bh + Al*Bh + Ah*Bl (fp32-emulated bf16 MFMA).
__global__ __launch_bounds__(256, 2) void ln_gemm_mfma_k(
    const float* __restrict__ x, const float* __restrict__ gamma,
    const float* __restrict__ beta,
    const unsigned short* __restrict__ wph,
    const unsigned short* __restrict__ wpl,
    const float* __restrict__ bl, const float* __restrict__ br,
    _Float16* __restrict__ xl16, float* __restrict__ xr, int n) {
  __shared__ unsigned short ah[128 * 136];
  __shared__ unsigned short al[128 * 136];

  const int t = threadIdx.x;
  const int blk = blockIdx.x * 128;

#pragma unroll
  for (int half = 0; half < 2; half++) {
    const int r = t >> 2, q = t & 3;
    const int row = half * 64 + r;
    const int node = blk + row;
    float4 v[8];
    float s = 0.f, s2 = 0.f;
    const float* xrow = x + (size_t)node * 128;
#pragma unroll
    for (int rep = 0; rep < 8; rep++) {
      float4 f = make_float4(0.f, 0.f, 0.f, 0.f);
      if (node < n) f = *(const float4*)(xrow + 4 * q + 16 * rep);
      v[rep] = f;
      s += f.x + f.y + f.z + f.w;
      s2 += f.x * f.x + f.y * f.y + f.z * f.z + f.w * f.w;
    }
    s += __shfl_xor(s, 1);  s += __shfl_xor(s, 2);
    s2 += __shfl_xor(s2, 1); s2 += __shfl_xor(s2, 2);
    const float mu = s * (1.f / 128.f);
    const float rs = rsqrtf(s2 * (1.f / 128.f) - mu * mu + 1e-5f);
#pragma unroll
    for (int rep = 0; rep < 8; rep++) {
      const int k0 = 4 * q + 16 * rep;
      const float4 g4 = *(const float4*)(gamma + k0);
      const float4 b4 = *(const float4*)(beta + k0);
      const float ev[4] = {v[rep].x, v[rep].y, v[rep].z, v[rep].w};
      const float gv[4] = {g4.x, g4.y, g4.z, g4.w};
      const float bv[4] = {b4.x, b4.y, b4.z, b4.w};
      unsigned short hs[4], ls[4];
#pragma unroll
      for (int i2 = 0; i2 < 4; i2++) {
        float xv = (ev[i2] - mu) * rs * gv[i2] + bv[i2];
        xv = fmaxf(xv, 0.f);
        const unsigned short h = f2bf(xv);
        hs[i2] = h;
        ls[i2] = f2bf(xv - bf2f(h));
      }
      *(ushort4*)(&ah[row * 136 + k0]) = make_ushort4(hs[0], hs[1], hs[2], hs[3]);
      *(ushort4*)(&al[row * 136 + k0]) = make_ushort4(ls[0], ls[1], ls[2], ls[3]);
    }
  }
  __syncthreads();

  const int lane = t & 63;
  const int w = t >> 6;
  const int mat = w >> 1;           // 0 -> xl16, 1 -> xr
  const int cbase = (w & 1) * 64;
  const int m16 = lane & 15;
  const int quad = lane >> 4;
  const float* const biasp = mat ? br : bl;

#pragma unroll
  for (int ct = 0; ct < 4; ct++) {
    const int c = cbase + ct * 16 + m16;
    bf16x8 Bh[4], Bl8[4];
#pragma unroll
    for (int kb = 0; kb < 4; kb++) {
      const int bo = ((mat * 4 + kb) * 128 + c) * 32 + quad * 8;
      Bh[kb]  = *(const bf16x8*)(wph + bo);
      Bl8[kb] = *(const bf16x8*)(wpl + bo);
    }
    const float bc = biasp[c];
#pragma unroll
    for (int rt = 0; rt < 8; rt++) {
      f32x4 a = {0.f, 0.f, 0.f, 0.f};
#pragma unroll
      for (int kb = 0; kb < 4; kb++) {
        const int ao = (rt * 16 + m16) * 136 + kb * 32 + quad * 8;
        const bf16x8 Ah  = *(const bf16x8*)(ah + ao);
        const bf16x8 Al8 = *(const bf16x8*)(al + ao);
        a = __builtin_amdgcn_mfma_f32_16x16x32_bf16(Ah,  Bh[kb],  a, 0, 0, 0);
        a = __builtin_amdgcn_mfma_f32_16x16x32_bf16(Al8, Bh[kb],  a, 0, 0, 0);
        a = __builtin_amdgcn_mfma_f32_16x16x32_bf16(Ah,  Bl8[kb], a, 0, 0, 0);
      }
      // C/D: col = lane&15, row = quad*4 + reg  [m89-verified]
#pragma unroll
      for (int g = 0; g < 4; g++) {
        const int row = blk + rt * 16 + quad * 4 + g;
        if (row < n) {
          const float o = a[g] + bc;
          if (mat == 0) {
            xl16[(size_t)row * 128 + c] = (_Float16)o;
          } else {
            __builtin_nontemporal_store(o, &xr[(size_t)row * 128 + c]);
          }
        }
      }
    }
  }
}

// ---------------- K2a: bucket histogram, LDS-aggregated --------------------
__global__ __launch_bounds__(256) void hist_lds_k(
    const int* __restrict__ dst_arr, int* __restrict__ bucket_cnt,
    int E, int NB) {
  __shared__ int h[NB_MAX];
  const int t = threadIdx.x;
  for (int b = t; b < NB; b += 256) h[b] = 0;
  __syncthreads();
  const int beg = blockIdx.x * BIN_T;
  const int end = min(beg + BIN_T, E);
  for (int j0 = beg + t * 4; j0 < end; j0 += 1024) {
    if (j0 + 4 <= end) {
      const int4 d4 = *(const int4*)(dst_arr + j0);
      atomicAdd(&h[d4.x >> 7], 1);
      atomicAdd(&h[d4.y >> 7], 1);
      atomicAdd(&h[d4.z >> 7], 1);
      atomicAdd(&h[d4.w >> 7], 1);
    } else {
      for (int j = j0; j < end; j++) atomicAdd(&h[dst_arr[j] >> 7], 1);
    }
  }
  __syncthreads();
  for (int b = t; b < NB; b += 256) {
    const int v = h[b];
    if (v) atomicAdd(&bucket_cnt[b], v);
  }
}

// ---------------- K2b: scan bucket counts (NB <= 1024, one block) ----------
__global__ __launch_bounds__(1024) void bucket_scan_k(
    const int* __restrict__ bucket_cnt, int* __restrict__ bucket_edge_off,
    int* __restrict__ bucket_cur, int* __restrict__ offsets,
    int NB, int N, int M) {
  __shared__ int lds[1024];
  const int t = threadIdx.x;
  const int v = (t < NB) ? bucket_cnt[t] : 0;
  lds[t] = v;
  __syncthreads();
  for (int d = 1; d < 1024; d <<= 1) {
    int u = 0;
    if (t >= d) u = lds[t - d];
    __syncthreads();
    lds[t] += u;
    __syncthreads();
  }
  if (t < NB) {
    const int excl = lds[t] - v;
    bucket_edge_off[t] = excl;
    bucket_cur[t] = excl;
    if (t == NB - 1) bucket_edge_off[NB] = lds[t];  // = E
  }
  if (t == 0) offsets[N] = M;
}

// ---------------- K2c: bin edges, block-aggregated two-phase ---------------
// Phase 1: LDS hist; one atomicAdd-return per (block,bucket) reserves a
// contiguous run. Phase 2: scatter via LDS cursor atomics.
// Edge packed UNSIGNED: (dst&127)<<25 | src   (src < 2^25).
__global__ __launch_bounds__(256) void bin2_k(
    const int* __restrict__ ei, int* __restrict__ bucket_cur,
    unsigned* __restrict__ binned, int E, int NB) {
  __shared__ int h[NB_MAX];
  __shared__ int cur[NB_MAX];
  const int t = threadIdx.x;
  for (int b = t; b < NB; b += 256) h[b] = 0;
  __syncthreads();
  const int beg = blockIdx.x * BIN_T;
  const int end = min(beg + BIN_T, E);
  // phase 1: local histogram
  for (int j0 = beg + t * 4; j0 < end; j0 += 1024) {
    if (j0 + 4 <= end) {
      const int4 d4 = *(const int4*)(ei + E + j0);
      atomicAdd(&h[d4.x >> 7], 1);
      atomicAdd(&h[d4.y >> 7], 1);
      atomicAdd(&h[d4.z >> 7], 1);
      atomicAdd(&h[d4.w >> 7], 1);
    } else {
      for (int j = j0; j < end; j++) atomicAdd(&h[ei[E + j] >> 7], 1);
    }
  }
  __syncthreads();
  // reserve global runs (one return-atomic per (block,bucket))
  for (int b = t; b < NB; b += 256) {
    const int v = h[b];
    cur[b] = v ? atomicAdd(&bucket_cur[b], v) : 0;
  }
  __syncthreads();
  // phase 2: scatter (chunk is L2-hot from phase 1)
  for (int j0 = beg + t * 4; j0 < end; j0 += 1024) {
    if (j0 + 4 <= end) {
      const int4 s4 = *(const int4*)(ei + j0);
      const int4 d4 = *(const int4*)(ei + E + j0);
      binned[atomicAdd(&cur[d4.x >> 7], 1)] =
          (((unsigned)d4.x & 127u) << 25) | (unsigned)s4.x;
      binned[atomicAdd(&cur[d4.y >> 7], 1)] =
          (((unsigned)d4.y & 127u) << 25) | (unsigned)s4.y;
      binned[atomicAdd(&cur[d4.z >> 7], 1)] =
          (((unsigned)d4.z & 127u) << 25) | (unsigned)s4.z;
      binned[atomicAdd(&cur[d4.w >> 7], 1)] =
          (((unsigned)d4.w & 127u) << 25) | (unsigned)s4.w;
    } else {
      for (int j = j0; j < end; j++) {
        const int s = ei[j], d = ei[E + j];
        binned[atomicAdd(&cur[d >> 7], 1)] =
            (((unsigned)d & 127u) << 25) | (unsigned)s;
      }
    }
  }
}

// ---------------- K2d: per-bucket CSR segment (LDS hist/scan/cursors) ------
// One block per bucket of 128 nodes. csr base = edge_off[b] + 128*b.
// Self-loop placed first in each node's segment.
__global__ __launch_bounds__(256) void csr_build_k(
    const unsigned* __restrict__ binned,
    const int* __restrict__ bucket_edge_off,
    int* __restrict__ csr_src, int* __restrict__ offsets, int N) {
  __shared__ int s_cnt[128];
  __shared__ int s_off[128];
  __shared__ int s_cur[128];
  const int b = blockIdx.x;
  const int t = threadIdx.x;
  const int eb = bucket_edge_off[b];
  const int ee = bucket_edge_off[b + 1];
  const int node0 = b << 7;
  if (t < 128) s_cnt[t] = 0;
  __syncthreads();
  for (int j = eb + t; j < ee; j += 256) {
    atomicAdd(&s_cnt[binned[j] >> 25], 1);   // unsigned shift: 0..127
  }
  __syncthreads();
  int w = 0;
  if (t < 128) w = (node0 + t < N) ? (s_cnt[t] + 1) : 0;  // +1 self-loop
  if (t < 128) s_off[t] = w;
  __syncthreads();
  for (int d = 1; d < 128; d <<= 1) {
    int u = 0;
    if (t < 128 && t >= d) u = s_off[t - d];
    __syncthreads();
    if (t < 128) s_off[t] += u;
    __syncthreads();
  }
  const int base = eb + node0;
  if (t < 128) {
    const int excl = s_off[t] - w;
    const int node = node0 + t;
    if (node < N) {
      offsets[node] = base + excl;
      csr_src[base + excl] = node;   // self-loop first
      s_cur[t] = excl + 1;
    }
  }
  __syncthreads();
  for (int j = eb + t; j < ee; j += 256) {
    const unsigned e = binned[j];
    const int pos = atomicAdd(&s_cur[e >> 25], 1);
    csr_src[base + pos] = (int)(e & 0x1ffffffu);
  }
}

// ---------------- K5: fused score + softmax + aggregate (wave/node) --------
__global__ __launch_bounds__(256) void agg_fused_k(
    const half2v* __restrict__ xl16, const float* __restrict__ xr,
    const float* __restrict__ att, const int* __restrict__ csr_src,
    const int* __restrict__ offsets, const float* __restrict__ bias,
    float* __restrict__ out, int n) {
  __shared__ float att_s[128];
  const int t = threadIdx.x;
  if (t < 128) att_s[t] = att[t];
  __syncthreads();

  const int wid = t >> 6;
  const int lane = t & 63;
  const int i = blockIdx.x * 4 + wid;
  if (i >= n) return;
  const int c = lane * 2;
  const int off = offsets[i];
  const int end = offsets[i + 1];

  const float2 b2 = *(const float2*)(bias + (c & 31));
  const float2 xr2 = *(const float2*)(xr + (size_t)i * 128 + c);
  const float2 at2 = *(const float2*)(att_s + c);

  float den = 0.f, accx = 0.f, accy = 0.f;

  half2v xvA[4];
#pragma unroll
  for (int k = 0; k < 4; k++) {
    const int jj = off + k < end ? off + k : end - 1;
    const int s = csr_src[jj];
    xvA[k] = xl16[(size_t)s * 64 + lane];
  }

  for (int j = off; j < end; j += 4) {
    float2 xv[4];
#pragma unroll
    for (int k = 0; k < 4; k++)
      xv[k] = make_float2((float)xvA[k].x, (float)xvA[k].y);
    const int jn = j + 4;
    if (jn < end) {
#pragma unroll
      for (int k = 0; k < 4; k++) {
        const int jj = jn + k < end ? jn + k : end - 1;
        const int s = csr_src[jj];
        xvA[k] = xl16[(size_t)s * 64 + lane];
      }
    }

    float p[4];
#pragma unroll
    for (int k = 0; k < 4; k++) {
      const float vx = xv[k].x + xr2.x;
      const float vy = xv[k].y + xr2.y;
      const float lx = fmaxf(vx, 0.2f * vx);
      const float ly = fmaxf(vy, 0.2f * vy);
      p[k] = fmaf(lx, at2.x, ly * at2.y);
    }
#pragma unroll
    for (int d = 1; d <= 8; d <<= 1) {
#pragma unroll
      for (int k = 0; k < 4; k++) p[k] += __shfl_xor(p[k], d);
    }
#pragma unroll
    for (int k = 0; k < 4; k++) {
      const float wgt = (j + k < end) ? __expf(p[k]) : 0.f;
      den += wgt;
      accx = fmaf(wgt, xv[k].x, accx);
      accy = fmaf(wgt, xv[k].y, accy);
    }
  }

  const float rd = 1.0f / (den + 1e-16f);
  accx *= rd;
  accy *= rd;
  accx += __shfl_xor(accx, 16); accy += __shfl_xor(accy, 16);
  accx += __shfl_xor(accx, 32); accy += __shfl_xor(accy, 32);
  if (lane < 16) {
    *(float2*)(out + (size_t)i * 32 + c) =
        make_float2(accx * 0.25f + b2.x, accy * 0.25f + b2.y);
  }
}

// ---------------------------------------------------------------------------
extern "C" void kernel_launch(void* const* d_in, const int* in_sizes, int n_in,
                              void* d_out, int out_size, void* d_ws,
                              size_t ws_size, hipStream_t stream) {
  const float* x     = (const float*)d_in[0];
  const int*   ei    = (const int*)d_in[1];
  const float* gamma = (const float*)d_in[2];
  const float* beta  = (const float*)d_in[3];
  const float* Wl    = (const float*)d_in[4];
  const float* bl    = (const float*)d_in[5];
  const float* Wr    = (const float*)d_in[6];
  const float* br    = (const float*)d_in[7];
  const float* att   = (const float*)d_in[8];
  const float* bias  = (const float*)d_in[9];
  float* out = (float*)d_out;

  const int N = in_sizes[0] / 128;
  const int E = in_sizes[1] / 2;
  const int M = E + N;
  const int NB = (N + 127) / 128;   // buckets of 128 nodes (<= NB_MAX)

  char* p = (char*)d_ws;
  size_t o = 0;
  auto alloc = [&](size_t bytes) -> void* {
    void* r = (void*)(p + o);
    o = (o + bytes + 255) & ~(size_t)255;
    return r;
  };
  // binned (E u32 = 6.4 MB) aliases xl16 (25.6 MB): CSR build finishes
  // before the GEMM writes xl16.
  _Float16* xl16   = (_Float16*)alloc((size_t)N * 128 * 2);
  unsigned* binned = (unsigned*)xl16;
  float* xr      = (float*)alloc((size_t)N * 128 * 4);
  int*   csr_src = (int*)alloc((size_t)M * 4);
  int*   offsets = (int*)alloc((size_t)(N + 1) * 4);
  int*   bucket_cnt = (int*)alloc((size_t)NB * 4);
  int*   bucket_off = (int*)alloc((size_t)(NB + 1) * 4);
  int*   bucket_cur = (int*)alloc((size_t)NB * 4);
  unsigned short* wph = (unsigned short*)alloc(2 * 128 * 128 * 2);
  unsigned short* wpl = (unsigned short*)alloc(2 * 128 * 128 * 2);
  (void)n_in; (void)out_size; (void)ws_size;

  const int nchunks = (E + BIN_T - 1) / BIN_T;

  // ---- CSR build ----
  hipMemsetAsync(bucket_cnt, 0, (size_t)NB * 4, stream);
  hist_lds_k<<<nchunks, 256, 0, stream>>>(ei + E, bucket_cnt, E, NB);
  bucket_scan_k<<<1, 1024, 0, stream>>>(bucket_cnt, bucket_off, bucket_cur,
                                        offsets, NB, N, M);
  bin2_k<<<nchunks, 256, 0, stream>>>(ei, bucket_cur, binned, E, NB);
  csr_build_k<<<NB, 256, 0, stream>>>(binned, bucket_off, csr_src, offsets, N);

  // ---- GEMM (overwrites xl16 region) ----
  pack_w_k<<<128, 256, 0, stream>>>(Wl, Wr, wph, wpl);
  ln_gemm_mfma_k<<<(N + 127) / 128, 256, 0, stream>>>(x, gamma, beta, wph, wpl,
                                                      bl, br, xl16, xr, N);

  // ---- fused attention aggregate ----
  agg_fused_k<<<(N + 3) / 4, 256, 0, stream>>>((const half2v*)xl16, xr, att,
                                               csr_src, offsets, bias, out, N);
}

// Round 8
// 340.176 us; speedup vs baseline: 3.4114x; 1.3284x over previous
//
#include <hip/hip_runtime.h>
#include <math.h>

// ---------------------------------------------------------------------------
// GATv2 block: LN+ReLU -> x_l(fp16)/x_r(fp32) GEMMs (split-bf16 MFMA, 64-row
// tile, LDS-staged full-line epilogue) -> LDS-aggregated bucketed CSR build ->
// fused score+softmax+aggregate -> head mean + bias.
// ---------------------------------------------------------------------------

typedef __bf16 bf16x8 __attribute__((ext_vector_type(8)));
typedef float f32x4 __attribute__((ext_vector_type(4)));
typedef _Float16 half2v __attribute__((ext_vector_type(2)));

#define BIN_T 16384          // edges per block in hist/bin kernels
#define NB_MAX 1024          // max buckets (N <= 131072)
#define AST 136              // A-tile row stride (shorts): 16B-aligned rows
#define FST 132              // fp32 staging row stride (floats)
#define HST 136              // fp16 staging row stride (halves)

static __device__ __forceinline__ unsigned short f2bf(float f) {
  union { float f; unsigned u; } v;
  v.f = f;
  const unsigned r = v.u + 0x7fffu + ((v.u >> 16) & 1u);  // RNE
  return (unsigned short)(r >> 16);
}
static __device__ __forceinline__ float bf2f(unsigned short h) {
  union { float f; unsigned u; } v;
  v.u = ((unsigned)h) << 16;
  return v.f;
}

// ---------------- K0: split W into bf16 hi/lo, B-fragment layout -----------
__global__ __launch_bounds__(256) void pack_w_k(
    const float* __restrict__ Wl, const float* __restrict__ Wr,
    unsigned short* __restrict__ wph, unsigned short* __restrict__ wpl) {
  const int idx = blockIdx.x * 256 + threadIdx.x;  // 0..32767
  const int mat = idx >> 14;
  const int rem = idx & 16383;   // k*128 + c
  const int k = rem >> 7;
  const int c = rem & 127;
  const float v = (mat ? Wr : Wl)[rem];
  const unsigned short h = f2bf(v);
  const unsigned short lo = f2bf(v - bf2f(h));
  const int po = ((mat * 4 + (k >> 5)) * 128 + c) * 32 + (k & 31);
  wph[po] = h;
  wpl[po] = lo;
}

// ---------------- K1: LN+ReLU + dual GEMM, 64-row tile ---------------------
// 4 waves: w0/w1 -> xl (fp16) cols 0-63/64-127 ; w2/w3 -> xr (fp32).
// D = Ah*Bh + Al*Bh + Ah*Bl. Accumulators held in registers; epilogue stages
// the C tile through LDS and stores full 128B lines (no partial-line RMW).
__global__ __launch_bounds__(256, 4) void ln_gemm_mfma_k(
    const float* __restrict__ x, const float* __restrict__ gamma,
    const float* __restrict__ beta,
    const unsigned short* __restrict__ wph,
    const unsigned short* __restrict__ wpl,
    const float* __restrict__ bl, const float* __restrict__ br,
    _Float16* __restrict__ xl16, float* __restrict__ xr, int n) {
  __shared__ char smem[64 * AST * 2 * 2];        // 34816 B, multi-purpose
  unsigned short* const ah = (unsigned short*)smem;       // [64][AST]
  unsigned short* const al = ah + 64 * AST;               // [64][AST]
  float* const stf = (float*)smem;                        // [64][FST] staging
  _Float16* const sth = (_Float16*)smem;                  // [64][HST] staging

  const int t = threadIdx.x;
  const int blk = blockIdx.x * 64;

  // ---- LN + ReLU + hi/lo split (registers; 4 lanes per node) ----
  {
    const int r = t >> 2, q = t & 3;
    const int node = blk + r;
    float4 v[8];
    float s = 0.f, s2 = 0.f;
    const float* xrow = x + (size_t)node * 128;
#pragma unroll
    for (int rep = 0; rep < 8; rep++) {
      float4 f = make_float4(0.f, 0.f, 0.f, 0.f);
      if (node < n) f = *(const float4*)(xrow + 4 * q + 16 * rep);
      v[rep] = f;
      s += f.x + f.y + f.z + f.w;
      s2 += f.x * f.x + f.y * f.y + f.z * f.z + f.w * f.w;
    }
    s += __shfl_xor(s, 1);  s += __shfl_xor(s, 2);
    s2 += __shfl_xor(s2, 1); s2 += __shfl_xor(s2, 2);
    const float mu = s * (1.f / 128.f);
    const float rs = rsqrtf(s2 * (1.f / 128.f) - mu * mu + 1e-5f);
#pragma unroll
    for (int rep = 0; rep < 8; rep++) {
      const int k0 = 4 * q + 16 * rep;
      const float4 g4 = *(const float4*)(gamma + k0);
      const float4 b4 = *(const float4*)(beta + k0);
      const float ev[4] = {v[rep].x, v[rep].y, v[rep].z, v[rep].w};
      const float gv[4] = {g4.x, g4.y, g4.z, g4.w};
      const float bv[4] = {b4.x, b4.y, b4.z, b4.w};
      unsigned short hs[4], ls[4];
#pragma unroll
      for (int i2 = 0; i2 < 4; i2++) {
        float xv = (ev[i2] - mu) * rs * gv[i2] + bv[i2];
        xv = fmaxf(xv, 0.f);
        const unsigned short h = f2bf(xv);
        hs[i2] = h;
        ls[i2] = f2bf(xv - bf2f(h));
      }
      *(ushort4*)(&ah[r * AST + k0]) = make_ushort4(hs[0], hs[1], hs[2], hs[3]);
      *(ushort4*)(&al[r * AST + k0]) = make_ushort4(ls[0], ls[1], ls[2], ls[3]);
    }
  }
  __syncthreads();

  // ---- MFMA phase: each wave = 64 rows x 64 cols ----
  const int lane = t & 63;
  const int w = t >> 6;
  const int mat = w >> 1;           // 0 -> xl16, 1 -> xr
  const int cbase = (w & 1) * 64;
  const int m16 = lane & 15;
  const int quad = lane >> 4;
  const float* const biasp = mat ? br : bl;

  f32x4 acc[4][4];                  // [ct][rt]
  float bc[4];
#pragma unroll
  for (int ct = 0; ct < 4; ct++) {
    const int c = cbase + ct * 16 + m16;
    bf16x8 Bh[4], Bl8[4];
#pragma unroll
    for (int kb = 0; kb < 4; kb++) {
      const int bo = ((mat * 4 + kb) * 128 + c) * 32 + quad * 8;
      Bh[kb]  = *(const bf16x8*)(wph + bo);
      Bl8[kb] = *(const bf16x8*)(wpl + bo);
    }
    bc[ct] = biasp[c];
#pragma unroll
    for (int rt = 0; rt < 4; rt++) {
      f32x4 a = {0.f, 0.f, 0.f, 0.f};
#pragma unroll
      for (int kb = 0; kb < 4; kb++) {
        const int ao = (rt * 16 + m16) * AST + kb * 32 + quad * 8;
        const bf16x8 Ah  = *(const bf16x8*)(ah + ao);
        const bf16x8 Al8 = *(const bf16x8*)(al + ao);
        a = __builtin_amdgcn_mfma_f32_16x16x32_bf16(Ah,  Bh[kb],  a, 0, 0, 0);
        a = __builtin_amdgcn_mfma_f32_16x16x32_bf16(Al8, Bh[kb],  a, 0, 0, 0);
        a = __builtin_amdgcn_mfma_f32_16x16x32_bf16(Ah,  Bl8[kb], a, 0, 0, 0);
      }
      acc[ct][rt] = a;
    }
  }

  // ---- Epilogue round A: xr (fp32) via LDS, full-line stores ----
  // C/D mapping: col = lane&15, row = quad*4 + reg  [m89-verified]
  __syncthreads();                  // MFMA reads of ah/al done
  if (mat == 1) {
#pragma unroll
    for (int ct = 0; ct < 4; ct++)
#pragma unroll
      for (int rt = 0; rt < 4; rt++)
#pragma unroll
        for (int g = 0; g < 4; g++)
          stf[(rt * 16 + quad * 4 + g) * FST + cbase + ct * 16 + m16] =
              acc[ct][rt][g] + bc[ct];
  }
  __syncthreads();
#pragma unroll
  for (int pass = 0; pass < 8; pass++) {
    const int idx = pass * 256 + t;         // 0..2047
    const int row = idx >> 5;
    const int c4 = (idx & 31) * 4;
    const int node = blk + row;
    if (node < n)
      *(float4*)(xr + (size_t)node * 128 + c4) =
          *(const float4*)(stf + row * FST + c4);
  }

  // ---- Epilogue round B: xl (fp16) via LDS, full-line stores ----
  __syncthreads();
  if (mat == 0) {
#pragma unroll
    for (int ct = 0; ct < 4; ct++)
#pragma unroll
      for (int rt = 0; rt < 4; rt++)
#pragma unroll
        for (int g = 0; g < 4; g++)
          sth[(rt * 16 + quad * 4 + g) * HST + cbase + ct * 16 + m16] =
              (_Float16)(acc[ct][rt][g] + bc[ct]);
  }
  __syncthreads();
  {
    unsigned short* const xlu = (unsigned short*)xl16;
#pragma unroll
    for (int pass = 0; pass < 4; pass++) {
      const int idx = pass * 256 + t;       // 0..1023
      const int row = idx >> 4;
      const int c8 = (idx & 15) * 8;
      const int node = blk + row;
      if (node < n)
        *(uint4*)(xlu + (size_t)node * 128 + c8) =
            *(const uint4*)((const unsigned short*)sth + row * HST + c8);
    }
  }
}

// ---------------- K2a: bucket histogram, LDS-aggregated --------------------
__global__ __launch_bounds__(256) void hist_lds_k(
    const int* __restrict__ dst_arr, int* __restrict__ bucket_cnt,
    int E, int NB) {
  __shared__ int h[NB_MAX];
  const int t = threadIdx.x;
  for (int b = t; b < NB; b += 256) h[b] = 0;
  __syncthreads();
  const int beg = blockIdx.x * BIN_T;
  const int end = min(beg + BIN_T, E);
  for (int j0 = beg + t * 4; j0 < end; j0 += 1024) {
    if (j0 + 4 <= end) {
      const int4 d4 = *(const int4*)(dst_arr + j0);
      atomicAdd(&h[d4.x >> 7], 1);
      atomicAdd(&h[d4.y >> 7], 1);
      atomicAdd(&h[d4.z >> 7], 1);
      atomicAdd(&h[d4.w >> 7], 1);
    } else {
      for (int j = j0; j < end; j++) atomicAdd(&h[dst_arr[j] >> 7], 1);
    }
  }
  __syncthreads();
  for (int b = t; b < NB; b += 256) {
    const int v = h[b];
    if (v) atomicAdd(&bucket_cnt[b], v);
  }
}

// ---------------- K2b: scan bucket counts (NB <= 1024, one block) ----------
__global__ __launch_bounds__(1024) void bucket_scan_k(
    const int* __restrict__ bucket_cnt, int* __restrict__ bucket_edge_off,
    int* __restrict__ bucket_cur, int* __restrict__ offsets,
    int NB, int N, int M) {
  __shared__ int lds[1024];
  const int t = threadIdx.x;
  const int v = (t < NB) ? bucket_cnt[t] : 0;
  lds[t] = v;
  __syncthreads();
  for (int d = 1; d < 1024; d <<= 1) {
    int u = 0;
    if (t >= d) u = lds[t - d];
    __syncthreads();
    lds[t] += u;
    __syncthreads();
  }
  if (t < NB) {
    const int excl = lds[t] - v;
    bucket_edge_off[t] = excl;
    bucket_cur[t] = excl;
    if (t == NB - 1) bucket_edge_off[NB] = lds[t];  // = E
  }
  if (t == 0) offsets[N] = M;
}

// ---------------- K2c: bin edges, block-aggregated two-phase ---------------
// Edge packed UNSIGNED: (dst&127)<<25 | src   (src < 2^25).
__global__ __launch_bounds__(256) void bin2_k(
    const int* __restrict__ ei, int* __restrict__ bucket_cur,
    unsigned* __restrict__ binned, int E, int NB) {
  __shared__ int h[NB_MAX];
  __shared__ int cur[NB_MAX];
  const int t = threadIdx.x;
  for (int b = t; b < NB; b += 256) h[b] = 0;
  __syncthreads();
  const int beg = blockIdx.x * BIN_T;
  const int end = min(beg + BIN_T, E);
  // phase 1: local histogram
  for (int j0 = beg + t * 4; j0 < end; j0 += 1024) {
    if (j0 + 4 <= end) {
      const int4 d4 = *(const int4*)(ei + E + j0);
      atomicAdd(&h[d4.x >> 7], 1);
      atomicAdd(&h[d4.y >> 7], 1);
      atomicAdd(&h[d4.z >> 7], 1);
      atomicAdd(&h[d4.w >> 7], 1);
    } else {
      for (int j = j0; j < end; j++) atomicAdd(&h[ei[E + j] >> 7], 1);
    }
  }
  __syncthreads();
  // reserve global runs (one return-atomic per (block,bucket))
  for (int b = t; b < NB; b += 256) {
    const int v = h[b];
    cur[b] = v ? atomicAdd(&bucket_cur[b], v) : 0;
  }
  __syncthreads();
  // phase 2: scatter (chunk is L2-hot from phase 1)
  for (int j0 = beg + t * 4; j0 < end; j0 += 1024) {
    if (j0 + 4 <= end) {
      const int4 s4 = *(const int4*)(ei + j0);
      const int4 d4 = *(const int4*)(ei + E + j0);
      binned[atomicAdd(&cur[d4.x >> 7], 1)] =
          (((unsigned)d4.x & 127u) << 25) | (unsigned)s4.x;
      binned[atomicAdd(&cur[d4.y >> 7], 1)] =
          (((unsigned)d4.y & 127u) << 25) | (unsigned)s4.y;
      binned[atomicAdd(&cur[d4.z >> 7], 1)] =
          (((unsigned)d4.z & 127u) << 25) | (unsigned)s4.z;
      binned[atomicAdd(&cur[d4.w >> 7], 1)] =
          (((unsigned)d4.w & 127u) << 25) | (unsigned)s4.w;
    } else {
      for (int j = j0; j < end; j++) {
        const int s = ei[j], d = ei[E + j];
        binned[atomicAdd(&cur[d >> 7], 1)] =
            (((unsigned)d & 127u) << 25) | (unsigned)s;
      }
    }
  }
}

// ---------------- K2d: per-bucket CSR segment (LDS hist/scan/cursors) ------
__global__ __launch_bounds__(256) void csr_build_k(
    const unsigned* __restrict__ binned,
    const int* __restrict__ bucket_edge_off,
    int* __restrict__ csr_src, int* __restrict__ offsets, int N) {
  __shared__ int s_cnt[128];
  __shared__ int s_off[128];
  __shared__ int s_cur[128];
  const int b = blockIdx.x;
  const int t = threadIdx.x;
  const int eb = bucket_edge_off[b];
  const int ee = bucket_edge_off[b + 1];
  const int node0 = b << 7;
  if (t < 128) s_cnt[t] = 0;
  __syncthreads();
  for (int j = eb + t; j < ee; j += 256) {
    atomicAdd(&s_cnt[binned[j] >> 25], 1);   // unsigned shift: 0..127
  }
  __syncthreads();
  int w = 0;
  if (t < 128) w = (node0 + t < N) ? (s_cnt[t] + 1) : 0;  // +1 self-loop
  if (t < 128) s_off[t] = w;
  __syncthreads();
  for (int d = 1; d < 128; d <<= 1) {
    int u = 0;
    if (t < 128 && t >= d) u = s_off[t - d];
    __syncthreads();
    if (t < 128) s_off[t] += u;
    __syncthreads();
  }
  const int base = eb + node0;
  if (t < 128) {
    const int excl = s_off[t] - w;
    const int node = node0 + t;
    if (node < N) {
      offsets[node] = base + excl;
      csr_src[base + excl] = node;   // self-loop first
      s_cur[t] = excl + 1;
    }
  }
  __syncthreads();
  for (int j = eb + t; j < ee; j += 256) {
    const unsigned e = binned[j];
    const int pos = atomicAdd(&s_cur[e >> 25], 1);
    csr_src[base + pos] = (int)(e & 0x1ffffffu);
  }
}

// ---------------- K5: fused score + softmax + aggregate (wave/node) --------
__global__ __launch_bounds__(256) void agg_fused_k(
    const half2v* __restrict__ xl16, const float* __restrict__ xr,
    const float* __restrict__ att, const int* __restrict__ csr_src,
    const int* __restrict__ offsets, const float* __restrict__ bias,
    float* __restrict__ out, int n) {
  __shared__ float att_s[128];
  const int t = threadIdx.x;
  if (t < 128) att_s[t] = att[t];
  __syncthreads();

  const int wid = t >> 6;
  const int lane = t & 63;
  const int i = blockIdx.x * 4 + wid;
  if (i >= n) return;
  const int c = lane * 2;
  const int off = offsets[i];
  const int end = offsets[i + 1];

  const float2 b2 = *(const float2*)(bias + (c & 31));
  const float2 xr2 = *(const float2*)(xr + (size_t)i * 128 + c);
  const float2 at2 = *(const float2*)(att_s + c);

  float den = 0.f, accx = 0.f, accy = 0.f;

  half2v xvA[4];
#pragma unroll
  for (int k = 0; k < 4; k++) {
    const int jj = off + k < end ? off + k : end - 1;
    const int s = csr_src[jj];
    xvA[k] = xl16[(size_t)s * 64 + lane];
  }

  for (int j = off; j < end; j += 4) {
    float2 xv[4];
#pragma unroll
    for (int k = 0; k < 4; k++)
      xv[k] = make_float2((float)xvA[k].x, (float)xvA[k].y);
    const int jn = j + 4;
    if (jn < end) {
#pragma unroll
      for (int k = 0; k < 4; k++) {
        const int jj = jn + k < end ? jn + k : end - 1;
        const int s = csr_src[jj];
        xvA[k] = xl16[(size_t)s * 64 + lane];
      }
    }

    float p[4];
#pragma unroll
    for (int k = 0; k < 4; k++) {
      const float vx = xv[k].x + xr2.x;
      const float vy = xv[k].y + xr2.y;
      const float lx = fmaxf(vx, 0.2f * vx);
      const float ly = fmaxf(vy, 0.2f * vy);
      p[k] = fmaf(lx, at2.x, ly * at2.y);
    }
#pragma unroll
    for (int d = 1; d <= 8; d <<= 1) {
#pragma unroll
      for (int k = 0; k < 4; k++) p[k] += __shfl_xor(p[k], d);
    }
#pragma unroll
    for (int k = 0; k < 4; k++) {
      const float wgt = (j + k < end) ? __expf(p[k]) : 0.f;
      den += wgt;
      accx = fmaf(wgt, xv[k].x, accx);
      accy = fmaf(wgt, xv[k].y, accy);
    }
  }

  const float rd = 1.0f / (den + 1e-16f);
  accx *= rd;
  accy *= rd;
  accx += __shfl_xor(accx, 16); accy += __shfl_xor(accy, 16);
  accx += __shfl_xor(accx, 32); accy += __shfl_xor(accy, 32);
  if (lane < 16) {
    *(float2*)(out + (size_t)i * 32 + c) =
        make_float2(accx * 0.25f + b2.x, accy * 0.25f + b2.y);
  }
}

// ---------------------------------------------------------------------------
extern "C" void kernel_launch(void* const* d_in, const int* in_sizes, int n_in,
                              void* d_out, int out_size, void* d_ws,
                              size_t ws_size, hipStream_t stream) {
  const float* x     = (const float*)d_in[0];
  const int*   ei    = (const int*)d_in[1];
  const float* gamma = (const float*)d_in[2];
  const float* beta  = (const float*)d_in[3];
  const float* Wl    = (const float*)d_in[4];
  const float* bl    = (const float*)d_in[5];
  const float* Wr    = (const float*)d_in[6];
  const float* br    = (const float*)d_in[7];
  const float* att   = (const float*)d_in[8];
  const float* bias  = (const float*)d_in[9];
  float* out = (float*)d_out;

  const int N = in_sizes[0] / 128;
  const int E = in_sizes[1] / 2;
  const int M = E + N;
  const int NB = (N + 127) / 128;   // buckets of 128 nodes (<= NB_MAX)

  char* p = (char*)d_ws;
  size_t o = 0;
  auto alloc = [&](size_t bytes) -> void* {
    void* r = (void*)(p + o);
    o = (o + bytes + 255) & ~(size_t)255;
    return r;
  };
  // binned (E u32 = 6.4 MB) aliases xl16 (25.6 MB): CSR build finishes
  // before the GEMM writes xl16.
  _Float16* xl16   = (_Float16*)alloc((size_t)N * 128 * 2);
  unsigned* binned = (unsigned*)xl16;
  float* xr      = (float*)alloc((size_t)N * 128 * 4);
  int*   csr_src = (int*)alloc((size_t)M * 4);
  int*   offsets = (int*)alloc((size_t)(N + 1) * 4);
  int*   bucket_cnt = (int*)alloc((size_t)NB * 4);
  int*   bucket_off = (int*)alloc((size_t)(NB + 1) * 4);
  int*   bucket_cur = (int*)alloc((size_t)NB * 4);
  unsigned short* wph = (unsigned short*)alloc(2 * 128 * 128 * 2);
  unsigned short* wpl = (unsigned short*)alloc(2 * 128 * 128 * 2);
  (void)n_in; (void)out_size; (void)ws_size;

  const int nchunks = (E + BIN_T - 1) / BIN_T;

  // ---- CSR build ----
  hipMemsetAsync(bucket_cnt, 0, (size_t)NB * 4, stream);
  hist_lds_k<<<nchunks, 256, 0, stream>>>(ei + E, bucket_cnt, E, NB);
  bucket_scan_k<<<1, 1024, 0, stream>>>(bucket_cnt, bucket_off, bucket_cur,
                                        offsets, NB, N, M);
  bin2_k<<<nchunks, 256, 0, stream>>>(ei, bucket_cur, binned, E, NB);
  csr_build_k<<<NB, 256, 0, stream>>>(binned, bucket_off, csr_src, offsets, N);

  // ---- GEMM (overwrites xl16 region) ----
  pack_w_k<<<128, 256, 0, stream>>>(Wl, Wr, wph, wpl);
  ln_gemm_mfma_k<<<(N + 63) / 64, 256, 0, stream>>>(x, gamma, beta, wph, wpl,
                                                    bl, br, xl16, xr, N);

  // ---- fused attention aggregate ----
  agg_fused_k<<<(N + 3) / 4, 256, 0, stream>>>((const half2v*)xl16, xr, att,
                                               csr_src, offsets, bias, out, N);
}

// Round 9
// 314.174 us; speedup vs baseline: 3.6938x; 1.0828x over previous
//
#include <hip/hip_runtime.h>
#include <math.h>

// ---------------------------------------------------------------------------
// GATv2 block: LN+ReLU -> x_l/x_r (both fp16) GEMMs (split-bf16 MFMA, 64-row
// tile, LDS-staged full-line epilogue) -> LDS-aggregated bucketed CSR build ->
// fused score+softmax+aggregate (packed-f16 math, 16 lanes/edge) -> mean+bias.
// ---------------------------------------------------------------------------

typedef __bf16 bf16x8 __attribute__((ext_vector_type(8)));
typedef float f32x4 __attribute__((ext_vector_type(4)));
typedef _Float16 h2 __attribute__((ext_vector_type(2)));

#define BIN_T 16384          // edges per block in hist/bin kernels
#define NB_MAX 1024          // max buckets (N <= 131072)
#define AST 136              // A-tile row stride (shorts): 16B-aligned rows
#define HST 136              // fp16 staging row stride (halves)

static __device__ __forceinline__ unsigned short f2bf(float f) {
  union { float f; unsigned u; } v;
  v.f = f;
  const unsigned r = v.u + 0x7fffu + ((v.u >> 16) & 1u);  // RNE
  return (unsigned short)(r >> 16);
}
static __device__ __forceinline__ float bf2f(unsigned short h) {
  union { float f; unsigned u; } v;
  v.u = ((unsigned)h) << 16;
  return v.f;
}

// ---------------- K0: split W into bf16 hi/lo, B-fragment layout -----------
__global__ __launch_bounds__(256) void pack_w_k(
    const float* __restrict__ Wl, const float* __restrict__ Wr,
    unsigned short* __restrict__ wph, unsigned short* __restrict__ wpl) {
  const int idx = blockIdx.x * 256 + threadIdx.x;  // 0..32767
  const int mat = idx >> 14;
  const int rem = idx & 16383;   // k*128 + c
  const int k = rem >> 7;
  const int c = rem & 127;
  const float v = (mat ? Wr : Wl)[rem];
  const unsigned short h = f2bf(v);
  const unsigned short lo = f2bf(v - bf2f(h));
  const int po = ((mat * 4 + (k >> 5)) * 128 + c) * 32 + (k & 31);
  wph[po] = h;
  wpl[po] = lo;
}

// ---------------- K1: LN+ReLU + dual GEMM, 64-row tile, fp16 outputs -------
// 4 waves: w0/w1 -> xl cols 0-63/64-127 ; w2/w3 -> xr. Both outputs fp16.
// D = Ah*Bh + Al*Bh + Ah*Bl. Epilogue stages C through LDS, full-line stores.
__global__ __launch_bounds__(256, 4) void ln_gemm_mfma_k(
    const float* __restrict__ x, const float* __restrict__ gamma,
    const float* __restrict__ beta,
    const unsigned short* __restrict__ wph,
    const unsigned short* __restrict__ wpl,
    const float* __restrict__ bl, const float* __restrict__ br,
    _Float16* __restrict__ xl16, _Float16* __restrict__ xr16, int n) {
  __shared__ char smem[64 * AST * 2 * 2];        // 34816 B, multi-purpose
  unsigned short* const ah = (unsigned short*)smem;       // [64][AST]
  unsigned short* const al = ah + 64 * AST;               // [64][AST]
  _Float16* const sth = (_Float16*)smem;                  // [64][HST] staging

  const int t = threadIdx.x;
  const int blk = blockIdx.x * 64;

  // ---- LN + ReLU + hi/lo split (registers; 4 lanes per node) ----
  {
    const int r = t >> 2, q = t & 3;
    const int node = blk + r;
    float4 v[8];
    float s = 0.f, s2 = 0.f;
    const float* xrow = x + (size_t)node * 128;
#pragma unroll
    for (int rep = 0; rep < 8; rep++) {
      float4 f = make_float4(0.f, 0.f, 0.f, 0.f);
      if (node < n) f = *(const float4*)(xrow + 4 * q + 16 * rep);
      v[rep] = f;
      s += f.x + f.y + f.z + f.w;
      s2 += f.x * f.x + f.y * f.y + f.z * f.z + f.w * f.w;
    }
    s += __shfl_xor(s, 1);  s += __shfl_xor(s, 2);
    s2 += __shfl_xor(s2, 1); s2 += __shfl_xor(s2, 2);
    const float mu = s * (1.f / 128.f);
    const float rs = rsqrtf(s2 * (1.f / 128.f) - mu * mu + 1e-5f);
#pragma unroll
    for (int rep = 0; rep < 8; rep++) {
      const int k0 = 4 * q + 16 * rep;
      const float4 g4 = *(const float4*)(gamma + k0);
      const float4 b4 = *(const float4*)(beta + k0);
      const float ev[4] = {v[rep].x, v[rep].y, v[rep].z, v[rep].w};
      const float gv[4] = {g4.x, g4.y, g4.z, g4.w};
      const float bv[4] = {b4.x, b4.y, b4.z, b4.w};
      unsigned short hs[4], ls[4];
#pragma unroll
      for (int i2 = 0; i2 < 4; i2++) {
        float xv = (ev[i2] - mu) * rs * gv[i2] + bv[i2];
        xv = fmaxf(xv, 0.f);
        const unsigned short h = f2bf(xv);
        hs[i2] = h;
        ls[i2] = f2bf(xv - bf2f(h));
      }
      *(ushort4*)(&ah[r * AST + k0]) = make_ushort4(hs[0], hs[1], hs[2], hs[3]);
      *(ushort4*)(&al[r * AST + k0]) = make_ushort4(ls[0], ls[1], ls[2], ls[3]);
    }
  }
  __syncthreads();

  // ---- MFMA phase: each wave = 64 rows x 64 cols ----
  const int lane = t & 63;
  const int w = t >> 6;
  const int mat = w >> 1;           // 0 -> xl16, 1 -> xr16
  const int cbase = (w & 1) * 64;
  const int m16 = lane & 15;
  const int quad = lane >> 4;
  const float* const biasp = mat ? br : bl;

  f32x4 acc[4][4];                  // [ct][rt]
  float bc[4];
#pragma unroll
  for (int ct = 0; ct < 4; ct++) {
    const int c = cbase + ct * 16 + m16;
    bf16x8 Bh[4], Bl8[4];
#pragma unroll
    for (int kb = 0; kb < 4; kb++) {
      const int bo = ((mat * 4 + kb) * 128 + c) * 32 + quad * 8;
      Bh[kb]  = *(const bf16x8*)(wph + bo);
      Bl8[kb] = *(const bf16x8*)(wpl + bo);
    }
    bc[ct] = biasp[c];
#pragma unroll
    for (int rt = 0; rt < 4; rt++) {
      f32x4 a = {0.f, 0.f, 0.f, 0.f};
#pragma unroll
      for (int kb = 0; kb < 4; kb++) {
        const int ao = (rt * 16 + m16) * AST + kb * 32 + quad * 8;
        const bf16x8 Ah  = *(const bf16x8*)(ah + ao);
        const bf16x8 Al8 = *(const bf16x8*)(al + ao);
        a = __builtin_amdgcn_mfma_f32_16x16x32_bf16(Ah,  Bh[kb],  a, 0, 0, 0);
        a = __builtin_amdgcn_mfma_f32_16x16x32_bf16(Al8, Bh[kb],  a, 0, 0, 0);
        a = __builtin_amdgcn_mfma_f32_16x16x32_bf16(Ah,  Bl8[kb], a, 0, 0, 0);
      }
      acc[ct][rt] = a;
    }
  }

  // ---- Epilogue: two rounds (xr16 then xl16) via LDS, full-line stores ----
  // C/D mapping: col = lane&15, row = quad*4 + reg  [m89-verified]
  unsigned short* const outs[2] = {(unsigned short*)xl16,
                                   (unsigned short*)xr16};
#pragma unroll
  for (int round = 0; round < 2; round++) {
    __syncthreads();
    if (mat == 1 - round) {   // round 0: xr waves stage; round 1: xl waves
#pragma unroll
      for (int ct = 0; ct < 4; ct++)
#pragma unroll
        for (int rt = 0; rt < 4; rt++)
#pragma unroll
          for (int g = 0; g < 4; g++)
            sth[(rt * 16 + quad * 4 + g) * HST + cbase + ct * 16 + m16] =
                (_Float16)(acc[ct][rt][g] + bc[ct]);
    }
    __syncthreads();
    unsigned short* const dst = outs[1 - round];
#pragma unroll
    for (int pass = 0; pass < 4; pass++) {
      const int idx = pass * 256 + t;       // 0..1023
      const int row = idx >> 4;
      const int c8 = (idx & 15) * 8;
      const int node = blk + row;
      if (node < n)
        *(uint4*)(dst + (size_t)node * 128 + c8) =
            *(const uint4*)((const unsigned short*)sth + row * HST + c8);
    }
  }
}

// ---------------- K2a: bucket histogram, LDS-aggregated --------------------
__global__ __launch_bounds__(256) void hist_lds_k(
    const int* __restrict__ dst_arr, int* __restrict__ bucket_cnt,
    int E, int NB) {
  __shared__ int h[NB_MAX];
  const int t = threadIdx.x;
  for (int b = t; b < NB; b += 256) h[b] = 0;
  __syncthreads();
  const int beg = blockIdx.x * BIN_T;
  const int end = min(beg + BIN_T, E);
  for (int j0 = beg + t * 4; j0 < end; j0 += 1024) {
    if (j0 + 4 <= end) {
      const int4 d4 = *(const int4*)(dst_arr + j0);
      atomicAdd(&h[d4.x >> 7], 1);
      atomicAdd(&h[d4.y >> 7], 1);
      atomicAdd(&h[d4.z >> 7], 1);
      atomicAdd(&h[d4.w >> 7], 1);
    } else {
      for (int j = j0; j < end; j++) atomicAdd(&h[dst_arr[j] >> 7], 1);
    }
  }
  __syncthreads();
  for (int b = t; b < NB; b += 256) {
    const int v = h[b];
    if (v) atomicAdd(&bucket_cnt[b], v);
  }
}

// ---------------- K2b: scan bucket counts (NB <= 1024, one block) ----------
__global__ __launch_bounds__(1024) void bucket_scan_k(
    const int* __restrict__ bucket_cnt, int* __restrict__ bucket_edge_off,
    int* __restrict__ bucket_cur, int* __restrict__ offsets,
    int NB, int N, int M) {
  __shared__ int lds[1024];
  const int t = threadIdx.x;
  const int v = (t < NB) ? bucket_cnt[t] : 0;
  lds[t] = v;
  __syncthreads();
  for (int d = 1; d < 1024; d <<= 1) {
    int u = 0;
    if (t >= d) u = lds[t - d];
    __syncthreads();
    lds[t] += u;
    __syncthreads();
  }
  if (t < NB) {
    const int excl = lds[t] - v;
    bucket_edge_off[t] = excl;
    bucket_cur[t] = excl;
    if (t == NB - 1) bucket_edge_off[NB] = lds[t];  // = E
  }
  if (t == 0) offsets[N] = M;
}

// ---------------- K2c: bin edges, block-aggregated two-phase ---------------
// Edge packed UNSIGNED: (dst&127)<<25 | src   (src < 2^25).
__global__ __launch_bounds__(256) void bin2_k(
    const int* __restrict__ ei, int* __restrict__ bucket_cur,
    unsigned* __restrict__ binned, int E, int NB) {
  __shared__ int h[NB_MAX];
  __shared__ int cur[NB_MAX];
  const int t = threadIdx.x;
  for (int b = t; b < NB; b += 256) h[b] = 0;
  __syncthreads();
  const int beg = blockIdx.x * BIN_T;
  const int end = min(beg + BIN_T, E);
  // phase 1: local histogram
  for (int j0 = beg + t * 4; j0 < end; j0 += 1024) {
    if (j0 + 4 <= end) {
      const int4 d4 = *(const int4*)(ei + E + j0);
      atomicAdd(&h[d4.x >> 7], 1);
      atomicAdd(&h[d4.y >> 7], 1);
      atomicAdd(&h[d4.z >> 7], 1);
      atomicAdd(&h[d4.w >> 7], 1);
    } else {
      for (int j = j0; j < end; j++) atomicAdd(&h[ei[E + j] >> 7], 1);
    }
  }
  __syncthreads();
  // reserve global runs (one return-atomic per (block,bucket))
  for (int b = t; b < NB; b += 256) {
    const int v = h[b];
    cur[b] = v ? atomicAdd(&bucket_cur[b], v) : 0;
  }
  __syncthreads();
  // phase 2: scatter (chunk is L2-hot from phase 1)
  for (int j0 = beg + t * 4; j0 < end; j0 += 1024) {
    if (j0 + 4 <= end) {
      const int4 s4 = *(const int4*)(ei + j0);
      const int4 d4 = *(const int4*)(ei + E + j0);
      binned[atomicAdd(&cur[d4.x >> 7], 1)] =
          (((unsigned)d4.x & 127u) << 25) | (unsigned)s4.x;
      binned[atomicAdd(&cur[d4.y >> 7], 1)] =
          (((unsigned)d4.y & 127u) << 25) | (unsigned)s4.y;
      binned[atomicAdd(&cur[d4.z >> 7], 1)] =
          (((unsigned)d4.z & 127u) << 25) | (unsigned)s4.z;
      binned[atomicAdd(&cur[d4.w >> 7], 1)] =
          (((unsigned)d4.w & 127u) << 25) | (unsigned)s4.w;
    } else {
      for (int j = j0; j < end; j++) {
        const int s = ei[j], d = ei[E + j];
        binned[atomicAdd(&cur[d >> 7], 1)] =
            (((unsigned)d & 127u) << 25) | (unsigned)s;
      }
    }
  }
}

// ---------------- K2d: per-bucket CSR segment (LDS hist/scan/cursors) ------
__global__ __launch_bounds__(256) void csr_build_k(
    const unsigned* __restrict__ binned,
    const int* __restrict__ bucket_edge_off,
    int* __restrict__ csr_src, int* __restrict__ offsets, int N) {
  __shared__ int s_cnt[128];
  __shared__ int s_off[128];
  __shared__ int s_cur[128];
  const int b = blockIdx.x;
  const int t = threadIdx.x;
  const int eb = bucket_edge_off[b];
  const int ee = bucket_edge_off[b + 1];
  const int node0 = b << 7;
  if (t < 128) s_cnt[t] = 0;
  __syncthreads();
  for (int j = eb + t; j < ee; j += 256) {
    atomicAdd(&s_cnt[binned[j] >> 25], 1);   // unsigned shift: 0..127
  }
  __syncthreads();
  int w = 0;
  if (t < 128) w = (node0 + t < N) ? (s_cnt[t] + 1) : 0;  // +1 self-loop
  if (t < 128) s_off[t] = w;
  __syncthreads();
  for (int d = 1; d < 128; d <<= 1) {
    int u = 0;
    if (t < 128 && t >= d) u = s_off[t - d];
    __syncthreads();
    if (t < 128) s_off[t] += u;
    __syncthreads();
  }
  const int base = eb + node0;
  if (t < 128) {
    const int excl = s_off[t] - w;
    const int node = node0 + t;
    if (node < N) {
      offsets[node] = base + excl;
      csr_src[base + excl] = node;   // self-loop first
      s_cur[t] = excl + 1;
    }
  }
  __syncthreads();
  for (int j = eb + t; j < ee; j += 256) {
    const unsigned e = binned[j];
    const int pos = atomicAdd(&s_cur[e >> 25], 1);
    csr_src[base + pos] = (int)(e & 0x1ffffffu);
  }
}

// ---------------- K5: fused score + softmax + aggregate --------------------
// One wave per dst node; 16 lanes per edge, 4 edges per wave iteration.
// Lane u = lane&15 owns dims 8u..8u+7 (4 x half2); head h = u>>2.
// Packed f16 math: v_pk_add/mul/max + v_dot2_f32_f16; fp32 exp/accum.
__global__ __launch_bounds__(256) void agg_fused_k(
    const uint4* __restrict__ xl4, const uint4* __restrict__ xr4,
    const float* __restrict__ att, const int* __restrict__ csr_src,
    const int* __restrict__ offsets, const float* __restrict__ bias,
    float* __restrict__ out, int n) {
  const int t = threadIdx.x;
  const int wid = t >> 6;
  const int lane = t & 63;
  const int i = blockIdx.x * 4 + wid;
  if (i >= n) return;
  const int u = lane & 15;   // dim-octet within the row
  const int g = lane >> 4;   // edge slot within the group of 4

  const int off = offsets[i];
  const int end = offsets[i + 1];

  // att (fp32) -> half2[4] for dims 8u..8u+7
  h2 at[4];
  {
    const float4 a0 = *(const float4*)(att + u * 8);
    const float4 a1 = *(const float4*)(att + u * 8 + 4);
    at[0] = h2{(_Float16)a0.x, (_Float16)a0.y};
    at[1] = h2{(_Float16)a0.z, (_Float16)a0.w};
    at[2] = h2{(_Float16)a1.x, (_Float16)a1.y};
    at[3] = h2{(_Float16)a1.z, (_Float16)a1.w};
  }
  // xr row (fp16), dims 8u..8u+7
  union U { uint4 u4; h2 h[4]; };
  U xru; xru.u4 = xr4[(size_t)i * 16 + u];

  const h2 slope = h2{(_Float16)0.2f, (_Float16)0.2f};

  float den = 0.f;
  float acc[8] = {0.f, 0.f, 0.f, 0.f, 0.f, 0.f, 0.f, 0.f};

  // prefetch first group
  int j = off + g;
  uint4 rawA = xl4[(size_t)csr_src[j < end ? j : end - 1] * 16 + u];

  for (int jb = off; jb < end; jb += 4) {
    U xv; xv.u4 = rawA;
    const int jn = jb + 4 + g;
    if (jb + 4 < end)
      rawA = xl4[(size_t)csr_src[jn < end ? jn : end - 1] * 16 + u];

    // score: att . leaky(xl + xr) over this lane's 8 dims
    float p = 0.f;
#pragma unroll
    for (int k = 0; k < 4; k++) {
      const h2 s = xv.h[k] + xru.h[k];
      const h2 l = __builtin_elementwise_max(s, s * slope);  // leaky 0.2
      p = __builtin_amdgcn_fdot2(l, at[k], p, false);
    }
    // reduce over the 4 lanes of this head
    p += __shfl_xor(p, 1);
    p += __shfl_xor(p, 2);

    const float wgt = (jb + g < end) ? __expf(p) : 0.f;
    den += wgt;
#pragma unroll
    for (int k = 0; k < 4; k++) {
      acc[2 * k]     = fmaf(wgt, (float)xv.h[k].x, acc[2 * k]);
      acc[2 * k + 1] = fmaf(wgt, (float)xv.h[k].y, acc[2 * k + 1]);
    }
  }

  // sum partials across the 4 edge-groups (lanes u, u+16, u+32, u+48)
  den += __shfl_xor(den, 16);
  den += __shfl_xor(den, 32);
#pragma unroll
  for (int m = 0; m < 8; m++) {
    acc[m] += __shfl_xor(acc[m], 16);
    acc[m] += __shfl_xor(acc[m], 32);
  }
  const float rd = 1.0f / (den + 1e-16f);
#pragma unroll
  for (int m = 0; m < 8; m++) acc[m] *= rd;
  // mean over heads: lanes u = 4h+q, sum over h via xor 4, 8
#pragma unroll
  for (int m = 0; m < 8; m++) {
    acc[m] += __shfl_xor(acc[m], 4);
    acc[m] += __shfl_xor(acc[m], 8);
  }
  if (lane < 4) {   // q = lane: out dims 8q..8q+7
    const float4 b0 = *(const float4*)(bias + lane * 8);
    const float4 b1 = *(const float4*)(bias + lane * 8 + 4);
    float4 o0 = make_float4(acc[0] * 0.25f + b0.x, acc[1] * 0.25f + b0.y,
                            acc[2] * 0.25f + b0.z, acc[3] * 0.25f + b0.w);
    float4 o1 = make_float4(acc[4] * 0.25f + b1.x, acc[5] * 0.25f + b1.y,
                            acc[6] * 0.25f + b1.z, acc[7] * 0.25f + b1.w);
    *(float4*)(out + (size_t)i * 32 + lane * 8) = o0;
    *(float4*)(out + (size_t)i * 32 + lane * 8 + 4) = o1;
  }
}

// ---------------------------------------------------------------------------
extern "C" void kernel_launch(void* const* d_in, const int* in_sizes, int n_in,
                              void* d_out, int out_size, void* d_ws,
                              size_t ws_size, hipStream_t stream) {
  const float* x     = (const float*)d_in[0];
  const int*   ei    = (const int*)d_in[1];
  const float* gamma = (const float*)d_in[2];
  const float* beta  = (const float*)d_in[3];
  const float* Wl    = (const float*)d_in[4];
  const float* bl    = (const float*)d_in[5];
  const float* Wr    = (const float*)d_in[6];
  const float* br    = (const float*)d_in[7];
  const float* att   = (const float*)d_in[8];
  const float* bias  = (const float*)d_in[9];
  float* out = (float*)d_out;

  const int N = in_sizes[0] / 128;
  const int E = in_sizes[1] / 2;
  const int M = E + N;
  const int NB = (N + 127) / 128;   // buckets of 128 nodes (<= NB_MAX)

  char* p = (char*)d_ws;
  size_t o = 0;
  auto alloc = [&](size_t bytes) -> void* {
    void* r = (void*)(p + o);
    o = (o + bytes + 255) & ~(size_t)255;
    return r;
  };
  // binned (E u32 = 6.4 MB) aliases xl16 (25.6 MB): CSR build finishes
  // before the GEMM writes xl16.
  _Float16* xl16   = (_Float16*)alloc((size_t)N * 128 * 2);
  unsigned* binned = (unsigned*)xl16;
  _Float16* xr16 = (_Float16*)alloc((size_t)N * 128 * 2);
  int*   csr_src = (int*)alloc((size_t)M * 4);
  int*   offsets = (int*)alloc((size_t)(N + 1) * 4);
  int*   bucket_cnt = (int*)alloc((size_t)NB * 4);
  int*   bucket_off = (int*)alloc((size_t)(NB + 1) * 4);
  int*   bucket_cur = (int*)alloc((size_t)NB * 4);
  unsigned short* wph = (unsigned short*)alloc(2 * 128 * 128 * 2);
  unsigned short* wpl = (unsigned short*)alloc(2 * 128 * 128 * 2);
  (void)n_in; (void)out_size; (void)ws_size;

  const int nchunks = (E + BIN_T - 1) / BIN_T;

  // ---- CSR build ----
  hipMemsetAsync(bucket_cnt, 0, (size_t)NB * 4, stream);
  hist_lds_k<<<nchunks, 256, 0, stream>>>(ei + E, bucket_cnt, E, NB);
  bucket_scan_k<<<1, 1024, 0, stream>>>(bucket_cnt, bucket_off, bucket_cur,
                                        offsets, NB, N, M);
  bin2_k<<<nchunks, 256, 0, stream>>>(ei, bucket_cur, binned, E, NB);
  csr_build_k<<<NB, 256, 0, stream>>>(binned, bucket_off, csr_src, offsets, N);

  // ---- GEMM (overwrites xl16 region) ----
  pack_w_k<<<128, 256, 0, stream>>>(Wl, Wr, wph, wpl);
  ln_gemm_mfma_k<<<(N + 63) / 64, 256, 0, stream>>>(x, gamma, beta, wph, wpl,
                                                    bl, br, xl16, xr16, N);

  // ---- fused attention aggregate ----
  agg_fused_k<<<(N + 3) / 4, 256, 0, stream>>>((const uint4*)xl16,
                                               (const uint4*)xr16, att,
                                               csr_src, offsets, bias, out, N);
}